// Round 4
// baseline (1283.879 us; speedup 1.0000x reference)
//
#include <hip/hip_runtime.h>
#include <hip/hip_bf16.h>

#define BSZ 4
#define SEQ 2048
#define DIM 2048
#define NH 16
#define HD 128
#define QK_LD 4096  // row stride of the per-batch packed Q|K workspace
#define SCALE 0.08838834764831845f

typedef __attribute__((ext_vector_type(8))) short bf16x8;
typedef __attribute__((ext_vector_type(4))) float f32x4;

// Async global->LDS, 16B per lane. LDS dest = wave-uniform base + lane*16.
#define GLDS16(g, l)                                                           \
  __builtin_amdgcn_global_load_lds(                                           \
      (const __attribute__((address_space(1))) void*)(g),                     \
      (__attribute__((address_space(3))) void*)(l), 16, 0, 0)

__device__ inline short f2b(float f) {
  __hip_bfloat16 h = __float2bfloat16(f);
  short s;
  __builtin_memcpy(&s, &h, 2);
  return s;
}

// Load 16 contiguous fp32, convert to bf16, store 32B to LDS (two b128).
__device__ inline void stage16(const float* gp, __hip_bfloat16* lp) {
  float4 q0 = ((const float4*)gp)[0], q1 = ((const float4*)gp)[1];
  float4 q2 = ((const float4*)gp)[2], q3 = ((const float4*)gp)[3];
  bf16x8 v0, v1;
  v0[0] = f2b(q0.x); v0[1] = f2b(q0.y); v0[2] = f2b(q0.z); v0[3] = f2b(q0.w);
  v0[4] = f2b(q1.x); v0[5] = f2b(q1.y); v0[6] = f2b(q1.z); v0[7] = f2b(q1.w);
  v1[0] = f2b(q2.x); v1[1] = f2b(q2.y); v1[2] = f2b(q2.z); v1[3] = f2b(q2.w);
  v1[4] = f2b(q3.x); v1[5] = f2b(q3.y); v1[6] = f2b(q3.z); v1[7] = f2b(q3.w);
  *(bf16x8*)lp = v0;
  *(bf16x8*)(lp + 8) = v1;
}

// Per-batch output slice base, dtype-aware (fl=1: bf16, fl=0: fp32).
__device__ inline char* out_slice(void* outv, int b, int fl) {
  return (char*)outv + (size_t)b * (size_t)SEQ * DIM * (fl ? 2u : 4u);
}

// ---------------------------------------------------------------------------
// Detect input dtype from w_qkv bit patterns; canonicalize qw/kw to bf16.
// bf16 data: bits[14:7] of each u32 = low-half bf16 exponent (in [96,160) for
// N(0,sigma) data essentially always).  fp32: those bits are mantissa ~uniform.
// ---------------------------------------------------------------------------
__global__ __launch_bounds__(256)
void detect_canon(const unsigned int* __restrict__ wbits,
                  const void* __restrict__ qw, const void* __restrict__ kw,
                  __hip_bfloat16* __restrict__ qwb,
                  __hip_bfloat16* __restrict__ kwb, int* __restrict__ flag) {
  __shared__ int cnt;
  const int t = threadIdx.x;
  if (t == 0) cnt = 0;
  __syncthreads();
  int local = 0;
  for (int i = 0; i < 4; ++i) {
    unsigned int e = (wbits[t * 4 + i] >> 7) & 0xFF;
    if (e >= 96 && e < 160) local++;
  }
  atomicAdd(&cnt, local);
  __syncthreads();
  const int f = (cnt >= 768) ? 1 : 0;  // 1 = bf16 tensors, 0 = fp32 tensors
  if (t == 0) *flag = f;
  if (t < 128)
    qwb[t] = f ? ((const __hip_bfloat16*)qw)[t]
               : __float2bfloat16(((const float*)qw)[t]);
  else
    kwb[t - 128] = f ? ((const __hip_bfloat16*)kw)[t - 128]
                     : __float2bfloat16(((const float*)kw)[t - 128]);
}

// ---------------------------------------------------------------------------
// Per-batch QKV projection: C = x_b @ w_qkv^T.  Q,K cols [0,4096) -> qk
// (bf16, ld 4096).  V cols [4096,6144) -> transposed bf16 into the batch's
// d_out slice as vt[(h*128+d)][s].  128x128 tile, BK=32, dual staging path.
// ---------------------------------------------------------------------------
__global__ __launch_bounds__(256)
void gemm_qkv(const void* __restrict__ xin, const void* __restrict__ win,
              __hip_bfloat16* __restrict__ qk, void* __restrict__ outv,
              const int* __restrict__ flag, int b) {
  __shared__ __hip_bfloat16 As[128 * 32];
  __shared__ __hip_bfloat16 Bs[128 * 32];
  const int t = threadIdx.x, wave = t >> 6, lane = t & 63;
  const int quad = lane >> 4, l16 = lane & 15;
  const int wm = (wave & 1) * 64, wn = (wave >> 1) * 64;
  const long bm = (long)blockIdx.x * 128, bn = (long)blockIdx.y * 128;
  const int fl = *flag;
  const __hip_bfloat16* Ab = (const __hip_bfloat16*)xin + (long)b * SEQ * DIM;
  const __hip_bfloat16* Bb = (const __hip_bfloat16*)win;
  const float* Af = (const float*)xin + (long)b * SEQ * DIM;
  const float* Bf = (const float*)win;

  f32x4 acc[4][4] = {};
  for (int k0 = 0; k0 < DIM; k0 += 32) {
    __syncthreads();
    if (fl) {
      for (int i = 0; i < 2; ++i) {
        int c = wave * 64 + lane + i * 256;  // 16B chunk id
        int row = c >> 2, kc = c & 3;        // tile [128 rows][32 k]
        GLDS16(Ab + (bm + row) * DIM + k0 + kc * 8, As + (wave * 64 + i * 256) * 8);
        GLDS16(Bb + (bn + row) * DIM + k0 + kc * 8, Bs + (wave * 64 + i * 256) * 8);
      }
    } else {
      int row = t >> 1, cb = k0 + (t & 1) * 16;
      stage16(Af + (bm + row) * DIM + cb, As + t * 16);
      stage16(Bf + (bn + row) * DIM + cb, Bs + t * 16);
    }
    __syncthreads();
    bf16x8 aF[4], bF[4];
    for (int mt = 0; mt < 4; ++mt)
      aF[mt] = *(const bf16x8*)(As + (wm + mt * 16 + l16) * 32 + quad * 8);
    for (int nt = 0; nt < 4; ++nt)
      bF[nt] = *(const bf16x8*)(Bs + (wn + nt * 16 + l16) * 32 + quad * 8);
    for (int mt = 0; mt < 4; ++mt)
      for (int nt = 0; nt < 4; ++nt)
        acc[mt][nt] = __builtin_amdgcn_mfma_f32_16x16x32_bf16(
            aF[mt], bF[nt], acc[mt][nt], 0, 0, 0);
  }

  // D layout: col = lane&15, row = quad*4 + reg
  if (bn < 4096) {  // Q|K block
    for (int mt = 0; mt < 4; ++mt) {
      long gr = bm + wm + mt * 16 + quad * 4;
      for (int nt = 0; nt < 4; ++nt) {
        long gc = bn + wn + nt * 16 + l16;
        for (int r = 0; r < 4; ++r)
          qk[(gr + r) * QK_LD + gc] = __float2bfloat16(acc[mt][nt][r]);
      }
    }
  } else {  // V block: transposed bf16 store into the batch's out slice
    __hip_bfloat16* vtb = (__hip_bfloat16*)out_slice(outv, b, fl);
    for (int mt = 0; mt < 4; ++mt) {
      long gr = bm + wm + mt * 16 + quad * 4;  // s
      for (int nt = 0; nt < 4; ++nt) {
        long col = bn - 4096 + wn + nt * 16 + l16;  // h*128 + d
        for (int r = 0; r < 4; ++r)
          vtb[col * SEQ + gr + r] = __float2bfloat16(acc[mt][nt][r]);
      }
    }
  }
}

// ---------------------------------------------------------------------------
// Per-batch per-head RMSNorm + RoPE on Q and K slots of qk, in place.
// One wave per (s, t in {q,k}, h); lane l owns pair (d=l, d=l+64).
// ---------------------------------------------------------------------------
__global__ __launch_bounds__(256)
void norm_rope(__hip_bfloat16* __restrict__ qk,
               const __hip_bfloat16* __restrict__ qwb,
               const __hip_bfloat16* __restrict__ kwb) {
  const int wave = threadIdx.x >> 6, lane = threadIdx.x & 63;
  const int gid = blockIdx.x * 4 + wave;  // [0, 65536)
  const int h = gid & 15, tt = (gid >> 4) & 1, s = gid >> 5;

  __hip_bfloat16* p = qk + (long)s * QK_LD + tt * DIM + h * HD;
  float v1 = __bfloat162float(p[lane]);
  float v2 = __bfloat162float(p[lane + 64]);

  float ss = v1 * v1 + v2 * v2;
  for (int off = 1; off < 64; off <<= 1) ss += __shfl_xor(ss, off);
  float inv = rsqrtf(ss * (1.0f / 128.0f) + 1e-6f);

  const __hip_bfloat16* w = tt ? kwb : qwb;
  float n1 = v1 * inv * __bfloat162float(w[lane]);
  float n2 = v2 * inv * __bfloat162float(w[lane + 64]);

  // freqs[i] = 32^(-i/64) = exp2(-5i/64);  ang = s * freq (fp32, matches np)
  float freq = exp2f(-5.0f * (float)lane * (1.0f / 64.0f));
  float ang = (float)s * freq;
  float c = cosf(ang), sn = sinf(ang);

  p[lane]      = __float2bfloat16(n1 * c - n2 * sn);
  p[lane + 64] = __float2bfloat16(n2 * c + n1 * sn);
}

// ---------------------------------------------------------------------------
// Per-batch flash attention, non-causal. Block = 64-query tile for one head;
// 4 waves x 16 query rows. Output in place into the Q-slot of qk (each block
// overwrites exactly the region whose Q only it reads, pre-staged in LDS).
// ---------------------------------------------------------------------------
__global__ __launch_bounds__(256)
void flash_attn(__hip_bfloat16* __restrict__ qk, void* __restrict__ outv,
                const int* __restrict__ flag, int b) {
  __shared__ __hip_bfloat16 Qs[4 * 64 * 32];     // [ks=4][row=64][32]
  __shared__ __hip_bfloat16 Ks[4 * 64 * 32];
  __shared__ __hip_bfloat16 Vs[2 * 128 * 32];    // [ks2=2][dim=128][32 keys]
  __shared__ __hip_bfloat16 Ps[4][2 * 16 * 32];  // per-wave [ks2=2][row=16][32]

  const int t = threadIdx.x, wave = t >> 6, lane = t & 63;
  const int quad = lane >> 4, l16 = lane & 15;
  const int q0 = blockIdx.x * 64, h = blockIdx.y;
  const int fl = *flag;
  __hip_bfloat16* Qg = qk + h * HD;
  const __hip_bfloat16* Kg = Qg + DIM;
  const __hip_bfloat16* Vt =
      (const __hip_bfloat16*)out_slice(outv, b, fl) + (long)h * HD * SEQ;

  // stage Q once: chunk f -> [ks = f>>8][row = (f>>2)&63][kk = f&3]
  for (int i = 0; i < 4; ++i) {
    int f = wave * 64 + lane + i * 256;
    int kk = f & 3, row = (f >> 2) & 63, ks = f >> 8;
    GLDS16(Qg + (long)(q0 + row) * QK_LD + ks * 32 + kk * 8,
           Qs + (wave * 64 + i * 256) * 8);
  }

  f32x4 oacc[8] = {};
  float m_run[4], l_run[4];
  for (int r = 0; r < 4; ++r) { m_run[r] = -1e30f; l_run[r] = 0.0f; }

  for (int j0 = 0; j0 < SEQ; j0 += 64) {
    __syncthreads();  // prev iter done reading Ks/Vs (Q drain at iter 0)
    for (int i = 0; i < 4; ++i) {
      int f = wave * 64 + lane + i * 256;
      int kk = f & 3, row = (f >> 2) & 63, ks = f >> 8;
      GLDS16(Kg + (long)(j0 + row) * QK_LD + ks * 32 + kk * 8,
             Ks + (wave * 64 + i * 256) * 8);
    }
    for (int i = 0; i < 4; ++i) {
      int f = wave * 64 + lane + i * 256;
      int kk = f & 3, dimr = (f >> 2) & 127, ks2 = f >> 9;
      GLDS16(Vt + (long)dimr * SEQ + j0 + ks2 * 32 + kk * 8,
             Vs + (wave * 64 + i * 256) * 8);
    }
    __syncthreads();  // drains vmcnt (GLDS) + barrier

    // S = Q K^T for this wave's 16 rows x 64 keys
    f32x4 sacc[4] = {};
    for (int ks = 0; ks < 4; ++ks) {
      bf16x8 aQ = *(const bf16x8*)(Qs + (ks * 64 + wave * 16 + l16) * 32 + quad * 8);
      for (int nt = 0; nt < 4; ++nt) {
        bf16x8 bK = *(const bf16x8*)(Ks + (ks * 64 + nt * 16 + l16) * 32 + quad * 8);
        sacc[nt] = __builtin_amdgcn_mfma_f32_16x16x32_bf16(aQ, bK, sacc[nt], 0, 0, 0);
      }
    }

    // online softmax; row = quad*4 + r, stats reduced across the 16-lane quad
    float p[4][4];
    for (int r = 0; r < 4; ++r) {
      float mx = -1e30f;
      for (int nt = 0; nt < 4; ++nt) {
        float sv = sacc[nt][r] * SCALE;
        p[nt][r] = sv;
        mx = fmaxf(mx, sv);
      }
      for (int off = 1; off < 16; off <<= 1) mx = fmaxf(mx, __shfl_xor(mx, off));
      float mnew = fmaxf(m_run[r], mx);
      float sum = 0.0f;
      for (int nt = 0; nt < 4; ++nt) {
        float e = __expf(p[nt][r] - mnew);
        p[nt][r] = e;
        sum += e;
      }
      for (int off = 1; off < 16; off <<= 1) sum += __shfl_xor(sum, off);
      float alpha = __expf(m_run[r] - mnew);
      l_run[r] = l_run[r] * alpha + sum;
      m_run[r] = mnew;
      for (int n = 0; n < 8; ++n) oacc[n][r] = oacc[n][r] * alpha;
    }

    // P: C-layout -> A-layout via LDS (k-chunked [ks2][16][32])
    __hip_bfloat16* pw = &Ps[wave][0];
    for (int r = 0; r < 4; ++r)
      for (int nt = 0; nt < 4; ++nt)
        pw[((nt >> 1) * 16 + quad * 4 + r) * 32 + (nt & 1) * 16 + l16] =
            __float2bfloat16(p[nt][r]);
    __syncthreads();

    // O += P @ V
    for (int ks2 = 0; ks2 < 2; ++ks2) {
      bf16x8 aP = *(const bf16x8*)(pw + (ks2 * 16 + l16) * 32 + quad * 8);
      for (int n = 0; n < 8; ++n) {
        bf16x8 bV = *(const bf16x8*)(Vs + (ks2 * 128 + n * 16 + l16) * 32 + quad * 8);
        oacc[n] = __builtin_amdgcn_mfma_f32_16x16x32_bf16(aP, bV, oacc[n], 0, 0, 0);
      }
    }
  }

  // epilogue: write O into this block's exclusive Q-slot region (bf16)
  for (int r = 0; r < 4; ++r) {
    float rl = 1.0f / l_run[r];
    long s = q0 + wave * 16 + quad * 4 + r;
    for (int n = 0; n < 8; ++n)
      qk[s * QK_LD + h * HD + n * 16 + l16] = __float2bfloat16(oacc[n][r] * rl);
  }
}

// ---------------------------------------------------------------------------
// Per-batch output projection: out_b = y_b @ w_proj^T.  A = qk Q-slot
// (bf16, lda 4096, GLDS).  B = w_proj (dual staging).  Store dtype by flag.
// ---------------------------------------------------------------------------
__global__ __launch_bounds__(256)
void gemm_proj(const __hip_bfloat16* __restrict__ A, const void* __restrict__ win,
               void* __restrict__ outv, const int* __restrict__ flag, int b) {
  __shared__ __hip_bfloat16 As[128 * 32];
  __shared__ __hip_bfloat16 Bs[128 * 32];
  const int t = threadIdx.x, wave = t >> 6, lane = t & 63;
  const int quad = lane >> 4, l16 = lane & 15;
  const int wm = (wave & 1) * 64, wn = (wave >> 1) * 64;
  const long bm = (long)blockIdx.x * 128, bn = (long)blockIdx.y * 128;
  const int fl = *flag;
  const __hip_bfloat16* Bb = (const __hip_bfloat16*)win;
  const float* Bf = (const float*)win;

  f32x4 acc[4][4] = {};
  for (int k0 = 0; k0 < DIM; k0 += 32) {
    __syncthreads();
    for (int i = 0; i < 2; ++i) {
      int c = wave * 64 + lane + i * 256;
      int row = c >> 2, kc = c & 3;
      GLDS16(A + (bm + row) * QK_LD + k0 + kc * 8, As + (wave * 64 + i * 256) * 8);
    }
    if (fl) {
      for (int i = 0; i < 2; ++i) {
        int c = wave * 64 + lane + i * 256;
        int row = c >> 2, kc = c & 3;
        GLDS16(Bb + (bn + row) * DIM + k0 + kc * 8, Bs + (wave * 64 + i * 256) * 8);
      }
    } else {
      int row = t >> 1, cb = k0 + (t & 1) * 16;
      stage16(Bf + (bn + row) * DIM + cb, Bs + t * 16);
    }
    __syncthreads();
    bf16x8 aF[4], bF[4];
    for (int mt = 0; mt < 4; ++mt)
      aF[mt] = *(const bf16x8*)(As + (wm + mt * 16 + l16) * 32 + quad * 8);
    for (int nt = 0; nt < 4; ++nt)
      bF[nt] = *(const bf16x8*)(Bs + (wn + nt * 16 + l16) * 32 + quad * 8);
    for (int mt = 0; mt < 4; ++mt)
      for (int nt = 0; nt < 4; ++nt)
        acc[mt][nt] = __builtin_amdgcn_mfma_f32_16x16x32_bf16(
            aF[mt], bF[nt], acc[mt][nt], 0, 0, 0);
  }

  char* Cb = out_slice(outv, b, fl);
  for (int mt = 0; mt < 4; ++mt) {
    long gr = bm + wm + mt * 16 + quad * 4;
    for (int nt = 0; nt < 4; ++nt) {
      long gc = bn + wn + nt * 16 + l16;
      for (int r = 0; r < 4; ++r) {
        float v = acc[mt][nt][r];
        long idx = (gr + r) * DIM + gc;
        if (fl) ((__hip_bfloat16*)Cb)[idx] = __float2bfloat16(v);
        else    ((float*)Cb)[idx] = v;
      }
    }
  }
}

// ---------------------------------------------------------------------------
extern "C" void kernel_launch(void* const* d_in, const int* in_sizes, int n_in,
                              void* d_out, int out_size, void* d_ws, size_t ws_size,
                              hipStream_t stream) {
  // ws layout: [0] int flag | byte 64: qwb[128] | byte 320: kwb[128]
  //            | byte 1024: qk bf16[2048][4096] (16 MiB, reused per batch)
  int* flag = (int*)d_ws;
  __hip_bfloat16* qwb = (__hip_bfloat16*)((char*)d_ws + 64);
  __hip_bfloat16* kwb = qwb + 128;
  __hip_bfloat16* qk = (__hip_bfloat16*)((char*)d_ws + 1024);

  detect_canon<<<1, 256, 0, stream>>>((const unsigned int*)d_in[1], d_in[3],
                                      d_in[4], qwb, kwb, flag);

  for (int b = 0; b < BSZ; ++b) {
    // Per-batch V^T (bf16) lives at the start of this batch's d_out slice;
    // flash consumes it, then gemm_proj overwrites the slice (stream-ordered).
    gemm_qkv<<<dim3(SEQ / 128, (3 * DIM) / 128), 256, 0, stream>>>(
        d_in[0], d_in[1], qk, d_out, flag, b);
    norm_rope<<<(SEQ * 2 * NH) / 4, 256, 0, stream>>>(qk, qwb, kwb);
    flash_attn<<<dim3(SEQ / 64, NH), 256, 0, stream>>>(qk, d_out, flag, b);
    gemm_proj<<<dim3(SEQ / 128, DIM / 128), 256, 0, stream>>>(
        qk, d_in[2], d_out, flag, b);
  }
}

// Round 5
// 916.860 us; speedup vs baseline: 1.4003x; 1.4003x over previous
//
#include <hip/hip_runtime.h>
#include <hip/hip_bf16.h>

#define BSZ 4
#define SEQ 2048
#define DIM 2048
#define NH 16
#define HD 128
#define QK_LD 4096  // row stride of packed Q|K workspace
#define SCALE 0.08838834764831845f

typedef __attribute__((ext_vector_type(8))) short bf16x8;
typedef __attribute__((ext_vector_type(4))) float f32x4;

// Async global->LDS, 16B per lane. LDS dest = wave-uniform base + lane*16.
#define GLDS16(g, l)                                                           \
  __builtin_amdgcn_global_load_lds(                                           \
      (const __attribute__((address_space(1))) void*)(g),                     \
      (__attribute__((address_space(3))) void*)(l), 16, 0, 0)

__device__ inline short f2b(float f) {
  __hip_bfloat16 h = __float2bfloat16(f);
  short s;
  __builtin_memcpy(&s, &h, 2);
  return s;
}

// Load 16 contiguous fp32, convert to bf16, store 32B to LDS (two b128).
__device__ inline void stage16(const float* gp, __hip_bfloat16* lp) {
  float4 q0 = ((const float4*)gp)[0], q1 = ((const float4*)gp)[1];
  float4 q2 = ((const float4*)gp)[2], q3 = ((const float4*)gp)[3];
  bf16x8 v0, v1;
  v0[0] = f2b(q0.x); v0[1] = f2b(q0.y); v0[2] = f2b(q0.z); v0[3] = f2b(q0.w);
  v0[4] = f2b(q1.x); v0[5] = f2b(q1.y); v0[6] = f2b(q1.z); v0[7] = f2b(q1.w);
  v1[0] = f2b(q2.x); v1[1] = f2b(q2.y); v1[2] = f2b(q2.z); v1[3] = f2b(q2.w);
  v1[4] = f2b(q3.x); v1[5] = f2b(q3.y); v1[6] = f2b(q3.z); v1[7] = f2b(q3.w);
  *(bf16x8*)lp = v0;
  *(bf16x8*)(lp + 8) = v1;
}

// Per-batch output slice base, dtype-aware (fl=1: bf16, fl=0: fp32).
__device__ inline char* out_slice(void* outv, int b, int fl) {
  return (char*)outv + (size_t)b * (size_t)SEQ * DIM * (fl ? 2u : 4u);
}

// ---------------------------------------------------------------------------
// Detect input dtype from w_qkv bit patterns; canonicalize qw/kw to bf16.
// ---------------------------------------------------------------------------
__global__ __launch_bounds__(256)
void detect_canon(const unsigned int* __restrict__ wbits,
                  const void* __restrict__ qw, const void* __restrict__ kw,
                  __hip_bfloat16* __restrict__ qwb,
                  __hip_bfloat16* __restrict__ kwb, int* __restrict__ flag) {
  __shared__ int cnt;
  const int t = threadIdx.x;
  if (t == 0) cnt = 0;
  __syncthreads();
  int local = 0;
  for (int i = 0; i < 4; ++i) {
    unsigned int e = (wbits[t * 4 + i] >> 7) & 0xFF;
    if (e >= 96 && e < 160) local++;
  }
  atomicAdd(&cnt, local);
  __syncthreads();
  const int f = (cnt >= 768) ? 1 : 0;  // 1 = bf16 tensors, 0 = fp32 tensors
  if (t == 0) *flag = f;
  if (t < 128)
    qwb[t] = f ? ((const __hip_bfloat16*)qw)[t]
               : __float2bfloat16(((const float*)qw)[t]);
  else
    kwb[t - 128] = f ? ((const __hip_bfloat16*)kw)[t - 128]
                     : __float2bfloat16(((const float*)kw)[t - 128]);
}

// ---------------------------------------------------------------------------
// Elementwise canonicalize a tensor to bf16 (8 elts/thread). fl=1: raw copy.
// ---------------------------------------------------------------------------
__global__ __launch_bounds__(256)
void convert_bf16(const void* __restrict__ in, __hip_bfloat16* __restrict__ out,
                  const int* __restrict__ flag) {
  const int fl = *flag;
  long i = ((long)blockIdx.x * 256 + threadIdx.x) * 8;
  if (fl) {
    *(float4*)(out + i) = *(const float4*)((const __hip_bfloat16*)in + i);
  } else {
    const float* p = (const float*)in + i;
    float4 a = ((const float4*)p)[0], b = ((const float4*)p)[1];
    bf16x8 o;
    o[0] = f2b(a.x); o[1] = f2b(a.y); o[2] = f2b(a.z); o[3] = f2b(a.w);
    o[4] = f2b(b.x); o[5] = f2b(b.y); o[6] = f2b(b.z); o[7] = f2b(b.w);
    *(bf16x8*)(out + i) = o;
  }
}

// ===========================================================================
// TIER A (big ws): full-batch bf16 GEMMs with global_load_lds on both sides.
// ===========================================================================

// C = A @ B^T.  A: xb [8192,2048] bf16.  B: wqkvb [6144,2048] bf16.
// Q,K cols [0,4096) -> qk (ld 4096).  V cols -> transposed bf16 into the
// owning batch's d_out slice as vt[(h*128+d)][s].
__global__ __launch_bounds__(256)
void gemm_qkv_full(const __hip_bfloat16* __restrict__ A,
                   const __hip_bfloat16* __restrict__ B,
                   __hip_bfloat16* __restrict__ qk, void* __restrict__ outv,
                   const int* __restrict__ flag) {
  __shared__ __hip_bfloat16 As[128 * 32];
  __shared__ __hip_bfloat16 Bs[128 * 32];
  const int t = threadIdx.x, wave = t >> 6, lane = t & 63;
  const int quad = lane >> 4, l16 = lane & 15;
  const int wm = (wave & 1) * 64, wn = (wave >> 1) * 64;
  const long bm = (long)blockIdx.x * 128, bn = (long)blockIdx.y * 128;
  const int fl = *flag;

  f32x4 acc[4][4] = {};
  for (int k0 = 0; k0 < DIM; k0 += 32) {
    __syncthreads();
    for (int i = 0; i < 2; ++i) {
      int c = wave * 64 + lane + i * 256;  // 16B chunk id
      int row = c >> 2, kc = c & 3;        // tile [128 rows][32 k]
      GLDS16(A + (bm + row) * DIM + k0 + kc * 8, As + (wave * 64 + i * 256) * 8);
      GLDS16(B + (bn + row) * DIM + k0 + kc * 8, Bs + (wave * 64 + i * 256) * 8);
    }
    __syncthreads();
    bf16x8 aF[4], bF[4];
    for (int mt = 0; mt < 4; ++mt)
      aF[mt] = *(const bf16x8*)(As + (wm + mt * 16 + l16) * 32 + quad * 8);
    for (int nt = 0; nt < 4; ++nt)
      bF[nt] = *(const bf16x8*)(Bs + (wn + nt * 16 + l16) * 32 + quad * 8);
    for (int mt = 0; mt < 4; ++mt)
      for (int nt = 0; nt < 4; ++nt)
        acc[mt][nt] = __builtin_amdgcn_mfma_f32_16x16x32_bf16(
            aF[mt], bF[nt], acc[mt][nt], 0, 0, 0);
  }

  if (bn < 4096) {  // Q|K block
    for (int mt = 0; mt < 4; ++mt) {
      long gr = bm + wm + mt * 16 + quad * 4;
      for (int nt = 0; nt < 4; ++nt) {
        long gc = bn + wn + nt * 16 + l16;
        for (int r = 0; r < 4; ++r)
          qk[(gr + r) * QK_LD + gc] = __float2bfloat16(acc[mt][nt][r]);
      }
    }
  } else {  // V block: transposed bf16 store into the owning batch's slice
    for (int mt = 0; mt < 4; ++mt) {
      long gr = bm + wm + mt * 16 + quad * 4;  // global row = b*2048+s
      __hip_bfloat16* vtb = (__hip_bfloat16*)out_slice(outv, (int)(gr >> 11), fl);
      long s = gr & 2047;
      for (int nt = 0; nt < 4; ++nt) {
        long col = bn - 4096 + wn + nt * 16 + l16;  // h*128 + d
        for (int r = 0; r < 4; ++r)
          vtb[col * SEQ + s + r] = __float2bfloat16(acc[mt][nt][r]);
      }
    }
  }
}

// Full-batch output projection: out = y @ w_proj^T.  A = qk Q-slot
// (bf16, lda 4096, 8192 rows).  B = wprojb bf16.  Store dtype by flag.
__global__ __launch_bounds__(256)
void gemm_proj_full(const __hip_bfloat16* __restrict__ A,
                    const __hip_bfloat16* __restrict__ B,
                    void* __restrict__ outv, const int* __restrict__ flag) {
  __shared__ __hip_bfloat16 As[128 * 32];
  __shared__ __hip_bfloat16 Bs[128 * 32];
  const int t = threadIdx.x, wave = t >> 6, lane = t & 63;
  const int quad = lane >> 4, l16 = lane & 15;
  const int wm = (wave & 1) * 64, wn = (wave >> 1) * 64;
  const long bm = (long)blockIdx.x * 128, bn = (long)blockIdx.y * 128;
  const int fl = *flag;

  f32x4 acc[4][4] = {};
  for (int k0 = 0; k0 < DIM; k0 += 32) {
    __syncthreads();
    for (int i = 0; i < 2; ++i) {
      int c = wave * 64 + lane + i * 256;
      int row = c >> 2, kc = c & 3;
      GLDS16(A + (bm + row) * QK_LD + k0 + kc * 8, As + (wave * 64 + i * 256) * 8);
      GLDS16(B + (bn + row) * DIM + k0 + kc * 8, Bs + (wave * 64 + i * 256) * 8);
    }
    __syncthreads();
    bf16x8 aF[4], bF[4];
    for (int mt = 0; mt < 4; ++mt)
      aF[mt] = *(const bf16x8*)(As + (wm + mt * 16 + l16) * 32 + quad * 8);
    for (int nt = 0; nt < 4; ++nt)
      bF[nt] = *(const bf16x8*)(Bs + (wn + nt * 16 + l16) * 32 + quad * 8);
    for (int mt = 0; mt < 4; ++mt)
      for (int nt = 0; nt < 4; ++nt)
        acc[mt][nt] = __builtin_amdgcn_mfma_f32_16x16x32_bf16(
            aF[mt], bF[nt], acc[mt][nt], 0, 0, 0);
  }

  for (int mt = 0; mt < 4; ++mt) {
    long gr = bm + wm + mt * 16 + quad * 4;
    for (int nt = 0; nt < 4; ++nt) {
      long gc = bn + wn + nt * 16 + l16;
      for (int r = 0; r < 4; ++r) {
        long idx = (gr + r) * DIM + gc;
        if (fl) ((__hip_bfloat16*)outv)[idx] = __float2bfloat16(acc[mt][nt][r]);
        else    ((float*)outv)[idx] = acc[mt][nt][r];
      }
    }
  }
}

// ===========================================================================
// TIER B (small ws): per-batch path, dual staging (known-good round-4 code).
// ===========================================================================

__global__ __launch_bounds__(256)
void gemm_qkv(const void* __restrict__ xin, const void* __restrict__ win,
              __hip_bfloat16* __restrict__ qk, void* __restrict__ outv,
              const int* __restrict__ flag, int b) {
  __shared__ __hip_bfloat16 As[128 * 32];
  __shared__ __hip_bfloat16 Bs[128 * 32];
  const int t = threadIdx.x, wave = t >> 6, lane = t & 63;
  const int quad = lane >> 4, l16 = lane & 15;
  const int wm = (wave & 1) * 64, wn = (wave >> 1) * 64;
  const long bm = (long)blockIdx.x * 128, bn = (long)blockIdx.y * 128;
  const int fl = *flag;
  const __hip_bfloat16* Ab = (const __hip_bfloat16*)xin + (long)b * SEQ * DIM;
  const __hip_bfloat16* Bb = (const __hip_bfloat16*)win;
  const float* Af = (const float*)xin + (long)b * SEQ * DIM;
  const float* Bf = (const float*)win;

  f32x4 acc[4][4] = {};
  for (int k0 = 0; k0 < DIM; k0 += 32) {
    __syncthreads();
    if (fl) {
      for (int i = 0; i < 2; ++i) {
        int c = wave * 64 + lane + i * 256;
        int row = c >> 2, kc = c & 3;
        GLDS16(Ab + (bm + row) * DIM + k0 + kc * 8, As + (wave * 64 + i * 256) * 8);
        GLDS16(Bb + (bn + row) * DIM + k0 + kc * 8, Bs + (wave * 64 + i * 256) * 8);
      }
    } else {
      int row = t >> 1, cb = k0 + (t & 1) * 16;
      stage16(Af + (bm + row) * DIM + cb, As + t * 16);
      stage16(Bf + (bn + row) * DIM + cb, Bs + t * 16);
    }
    __syncthreads();
    bf16x8 aF[4], bF[4];
    for (int mt = 0; mt < 4; ++mt)
      aF[mt] = *(const bf16x8*)(As + (wm + mt * 16 + l16) * 32 + quad * 8);
    for (int nt = 0; nt < 4; ++nt)
      bF[nt] = *(const bf16x8*)(Bs + (wn + nt * 16 + l16) * 32 + quad * 8);
    for (int mt = 0; mt < 4; ++mt)
      for (int nt = 0; nt < 4; ++nt)
        acc[mt][nt] = __builtin_amdgcn_mfma_f32_16x16x32_bf16(
            aF[mt], bF[nt], acc[mt][nt], 0, 0, 0);
  }

  if (bn < 4096) {
    for (int mt = 0; mt < 4; ++mt) {
      long gr = bm + wm + mt * 16 + quad * 4;
      for (int nt = 0; nt < 4; ++nt) {
        long gc = bn + wn + nt * 16 + l16;
        for (int r = 0; r < 4; ++r)
          qk[(gr + r) * QK_LD + gc] = __float2bfloat16(acc[mt][nt][r]);
      }
    }
  } else {
    __hip_bfloat16* vtb = (__hip_bfloat16*)out_slice(outv, b, fl);
    for (int mt = 0; mt < 4; ++mt) {
      long gr = bm + wm + mt * 16 + quad * 4;
      for (int nt = 0; nt < 4; ++nt) {
        long col = bn - 4096 + wn + nt * 16 + l16;
        for (int r = 0; r < 4; ++r)
          vtb[col * SEQ + gr + r] = __float2bfloat16(acc[mt][nt][r]);
      }
    }
  }
}

__global__ __launch_bounds__(256)
void gemm_proj(const __hip_bfloat16* __restrict__ A, const void* __restrict__ win,
               void* __restrict__ outv, const int* __restrict__ flag, int b) {
  __shared__ __hip_bfloat16 As[128 * 32];
  __shared__ __hip_bfloat16 Bs[128 * 32];
  const int t = threadIdx.x, wave = t >> 6, lane = t & 63;
  const int quad = lane >> 4, l16 = lane & 15;
  const int wm = (wave & 1) * 64, wn = (wave >> 1) * 64;
  const long bm = (long)blockIdx.x * 128, bn = (long)blockIdx.y * 128;
  const int fl = *flag;
  const __hip_bfloat16* Bb = (const __hip_bfloat16*)win;
  const float* Bf = (const float*)win;

  f32x4 acc[4][4] = {};
  for (int k0 = 0; k0 < DIM; k0 += 32) {
    __syncthreads();
    for (int i = 0; i < 2; ++i) {
      int c = wave * 64 + lane + i * 256;
      int row = c >> 2, kc = c & 3;
      GLDS16(A + (bm + row) * QK_LD + k0 + kc * 8, As + (wave * 64 + i * 256) * 8);
    }
    if (fl) {
      for (int i = 0; i < 2; ++i) {
        int c = wave * 64 + lane + i * 256;
        int row = c >> 2, kc = c & 3;
        GLDS16(Bb + (bn + row) * DIM + k0 + kc * 8, Bs + (wave * 64 + i * 256) * 8);
      }
    } else {
      int row = t >> 1, cb = k0 + (t & 1) * 16;
      stage16(Bf + (bn + row) * DIM + cb, Bs + t * 16);
    }
    __syncthreads();
    bf16x8 aF[4], bF[4];
    for (int mt = 0; mt < 4; ++mt)
      aF[mt] = *(const bf16x8*)(As + (wm + mt * 16 + l16) * 32 + quad * 8);
    for (int nt = 0; nt < 4; ++nt)
      bF[nt] = *(const bf16x8*)(Bs + (wn + nt * 16 + l16) * 32 + quad * 8);
    for (int mt = 0; mt < 4; ++mt)
      for (int nt = 0; nt < 4; ++nt)
        acc[mt][nt] = __builtin_amdgcn_mfma_f32_16x16x32_bf16(
            aF[mt], bF[nt], acc[mt][nt], 0, 0, 0);
  }

  char* Cb = out_slice(outv, b, fl);
  for (int mt = 0; mt < 4; ++mt) {
    long gr = bm + wm + mt * 16 + quad * 4;
    for (int nt = 0; nt < 4; ++nt) {
      long gc = bn + wn + nt * 16 + l16;
      for (int r = 0; r < 4; ++r) {
        long idx = (gr + r) * DIM + gc;
        if (fl) ((__hip_bfloat16*)Cb)[idx] = __float2bfloat16(acc[mt][nt][r]);
        else    ((float*)Cb)[idx] = acc[mt][nt][r];
      }
    }
  }
}

// ===========================================================================
// Shared: norm_rope (per-row; RoPE angle uses row&2047) and flash_attn.
// ===========================================================================

__global__ __launch_bounds__(256)
void norm_rope(__hip_bfloat16* __restrict__ qk,
               const __hip_bfloat16* __restrict__ qwb,
               const __hip_bfloat16* __restrict__ kwb) {
  const int wave = threadIdx.x >> 6, lane = threadIdx.x & 63;
  const int gid = blockIdx.x * 4 + wave;
  const int h = gid & 15, tt = (gid >> 4) & 1, row = gid >> 5;
  const int s = row & 2047;

  __hip_bfloat16* p = qk + (long)row * QK_LD + tt * DIM + h * HD;
  float v1 = __bfloat162float(p[lane]);
  float v2 = __bfloat162float(p[lane + 64]);

  float ss = v1 * v1 + v2 * v2;
  for (int off = 1; off < 64; off <<= 1) ss += __shfl_xor(ss, off);
  float inv = rsqrtf(ss * (1.0f / 128.0f) + 1e-6f);

  const __hip_bfloat16* w = tt ? kwb : qwb;
  float n1 = v1 * inv * __bfloat162float(w[lane]);
  float n2 = v2 * inv * __bfloat162float(w[lane + 64]);

  float freq = exp2f(-5.0f * (float)lane * (1.0f / 64.0f));
  float ang = (float)s * freq;
  float c = cosf(ang), sn = sinf(ang);

  p[lane]      = __float2bfloat16(n1 * c - n2 * sn);
  p[lane + 64] = __float2bfloat16(n2 * c + n1 * sn);
}

// qk = per-batch base (caller offsets). Output in place into the Q-slot.
__global__ __launch_bounds__(256)
void flash_attn(__hip_bfloat16* __restrict__ qk, void* __restrict__ outv,
                const int* __restrict__ flag, int b) {
  __shared__ __hip_bfloat16 Qs[4 * 64 * 32];
  __shared__ __hip_bfloat16 Ks[4 * 64 * 32];
  __shared__ __hip_bfloat16 Vs[2 * 128 * 32];
  __shared__ __hip_bfloat16 Ps[4][2 * 16 * 32];

  const int t = threadIdx.x, wave = t >> 6, lane = t & 63;
  const int quad = lane >> 4, l16 = lane & 15;
  const int q0 = blockIdx.x * 64, h = blockIdx.y;
  const int fl = *flag;
  __hip_bfloat16* Qg = qk + h * HD;
  const __hip_bfloat16* Kg = Qg + DIM;
  const __hip_bfloat16* Vt =
      (const __hip_bfloat16*)out_slice(outv, b, fl) + (long)h * HD * SEQ;

  for (int i = 0; i < 4; ++i) {
    int f = wave * 64 + lane + i * 256;
    int kk = f & 3, row = (f >> 2) & 63, ks = f >> 8;
    GLDS16(Qg + (long)(q0 + row) * QK_LD + ks * 32 + kk * 8,
           Qs + (wave * 64 + i * 256) * 8);
  }

  f32x4 oacc[8] = {};
  float m_run[4], l_run[4];
  for (int r = 0; r < 4; ++r) { m_run[r] = -1e30f; l_run[r] = 0.0f; }

  for (int j0 = 0; j0 < SEQ; j0 += 64) {
    __syncthreads();
    for (int i = 0; i < 4; ++i) {
      int f = wave * 64 + lane + i * 256;
      int kk = f & 3, row = (f >> 2) & 63, ks = f >> 8;
      GLDS16(Kg + (long)(j0 + row) * QK_LD + ks * 32 + kk * 8,
             Ks + (wave * 64 + i * 256) * 8);
    }
    for (int i = 0; i < 4; ++i) {
      int f = wave * 64 + lane + i * 256;
      int kk = f & 3, dimr = (f >> 2) & 127, ks2 = f >> 9;
      GLDS16(Vt + (long)dimr * SEQ + j0 + ks2 * 32 + kk * 8,
             Vs + (wave * 64 + i * 256) * 8);
    }
    __syncthreads();

    f32x4 sacc[4] = {};
    for (int ks = 0; ks < 4; ++ks) {
      bf16x8 aQ = *(const bf16x8*)(Qs + (ks * 64 + wave * 16 + l16) * 32 + quad * 8);
      for (int nt = 0; nt < 4; ++nt) {
        bf16x8 bK = *(const bf16x8*)(Ks + (ks * 64 + nt * 16 + l16) * 32 + quad * 8);
        sacc[nt] = __builtin_amdgcn_mfma_f32_16x16x32_bf16(aQ, bK, sacc[nt], 0, 0, 0);
      }
    }

    float p[4][4];
    for (int r = 0; r < 4; ++r) {
      float mx = -1e30f;
      for (int nt = 0; nt < 4; ++nt) {
        float sv = sacc[nt][r] * SCALE;
        p[nt][r] = sv;
        mx = fmaxf(mx, sv);
      }
      for (int off = 1; off < 16; off <<= 1) mx = fmaxf(mx, __shfl_xor(mx, off));
      float mnew = fmaxf(m_run[r], mx);
      float sum = 0.0f;
      for (int nt = 0; nt < 4; ++nt) {
        float e = __expf(p[nt][r] - mnew);
        p[nt][r] = e;
        sum += e;
      }
      for (int off = 1; off < 16; off <<= 1) sum += __shfl_xor(sum, off);
      float alpha = __expf(m_run[r] - mnew);
      l_run[r] = l_run[r] * alpha + sum;
      m_run[r] = mnew;
      for (int n = 0; n < 8; ++n) oacc[n][r] = oacc[n][r] * alpha;
    }

    __hip_bfloat16* pw = &Ps[wave][0];
    for (int r = 0; r < 4; ++r)
      for (int nt = 0; nt < 4; ++nt)
        pw[((nt >> 1) * 16 + quad * 4 + r) * 32 + (nt & 1) * 16 + l16] =
            __float2bfloat16(p[nt][r]);
    __syncthreads();

    for (int ks2 = 0; ks2 < 2; ++ks2) {
      bf16x8 aP = *(const bf16x8*)(pw + (ks2 * 16 + l16) * 32 + quad * 8);
      for (int n = 0; n < 8; ++n) {
        bf16x8 bV = *(const bf16x8*)(Vs + (ks2 * 128 + n * 16 + l16) * 32 + quad * 8);
        oacc[n] = __builtin_amdgcn_mfma_f32_16x16x32_bf16(aP, bV, oacc[n], 0, 0, 0);
      }
    }
  }

  for (int r = 0; r < 4; ++r) {
    float rl = 1.0f / l_run[r];
    long s = q0 + wave * 16 + quad * 4 + r;
    for (int n = 0; n < 8; ++n)
      qk[s * QK_LD + h * HD + n * 16 + l16] = __float2bfloat16(oacc[n][r] * rl);
  }
}

// ---------------------------------------------------------------------------
extern "C" void kernel_launch(void* const* d_in, const int* in_sizes, int n_in,
                              void* d_out, int out_size, void* d_ws, size_t ws_size,
                              hipStream_t stream) {
  int* flag = (int*)d_ws;
  __hip_bfloat16* qwb = (__hip_bfloat16*)((char*)d_ws + 64);
  __hip_bfloat16* kwb = qwb + 128;
  char* base = (char*)d_ws + 1024;

  detect_canon<<<1, 256, 0, stream>>>((const unsigned int*)d_in[1], d_in[3],
                                      d_in[4], qwb, kwb, flag);

  const size_t MB = 1024ull * 1024ull;
  const size_t NEED_A = 1024 + 128 * MB;  // xb 32 + wqkvb 24 + wprojb 8 + qk 64

  if (ws_size >= NEED_A) {
    // ---- Tier A: full-batch bf16 path ----
    __hip_bfloat16* xb     = (__hip_bfloat16*)base;              // 32 MiB
    __hip_bfloat16* wqkvb  = (__hip_bfloat16*)(base + 32 * MB);  // 24 MiB
    __hip_bfloat16* wprojb = (__hip_bfloat16*)(base + 56 * MB);  //  8 MiB
    __hip_bfloat16* qk     = (__hip_bfloat16*)(base + 64 * MB);  // 64 MiB

    convert_bf16<<<(BSZ * SEQ * DIM) / 2048, 256, 0, stream>>>(d_in[0], xb, flag);
    convert_bf16<<<(3 * DIM * DIM) / 2048, 256, 0, stream>>>(d_in[1], wqkvb, flag);
    convert_bf16<<<(DIM * DIM) / 2048, 256, 0, stream>>>(d_in[2], wprojb, flag);

    gemm_qkv_full<<<dim3((BSZ * SEQ) / 128, (3 * DIM) / 128), 256, 0, stream>>>(
        xb, wqkvb, qk, d_out, flag);
    norm_rope<<<(BSZ * SEQ * 2 * NH) / 4, 256, 0, stream>>>(qk, qwb, kwb);
    for (int b = 0; b < BSZ; ++b)
      flash_attn<<<dim3(SEQ / 64, NH), 256, 0, stream>>>(
          qk + (long)b * SEQ * QK_LD, d_out, flag, b);
    gemm_proj_full<<<dim3((BSZ * SEQ) / 128, DIM / 128), 256, 0, stream>>>(
        qk, wprojb, d_out, flag);
  } else {
    // ---- Tier B: per-batch fallback (round-4 known-good) ----
    __hip_bfloat16* qk = (__hip_bfloat16*)base;  // 16 MiB, reused per batch
    for (int b = 0; b < BSZ; ++b) {
      gemm_qkv<<<dim3(SEQ / 128, (3 * DIM) / 128), 256, 0, stream>>>(
          d_in[0], d_in[1], qk, d_out, flag, b);
      norm_rope<<<(SEQ * 2 * NH) / 4, 256, 0, stream>>>(qk, qwb, kwb);
      flash_attn<<<dim3(SEQ / 64, NH), 256, 0, stream>>>(qk, d_out, flag, b);
      gemm_proj<<<dim3(SEQ / 128, DIM / 128), 256, 0, stream>>>(
          qk, d_in[2], d_out, flag, b);
    }
  }
}

// Round 6
// 863.489 us; speedup vs baseline: 1.4869x; 1.0618x over previous
//
#include <hip/hip_runtime.h>
#include <hip/hip_bf16.h>

#define BSZ 4
#define SEQ 2048
#define DIM 2048
#define NH 16
#define HD 128
#define QK_LD 4096  // row stride of packed Q|K workspace
#define SCALE 0.08838834764831845f

typedef __attribute__((ext_vector_type(8))) short bf16x8;
typedef __attribute__((ext_vector_type(4))) float f32x4;

// Async global->LDS, 16B per lane. LDS dest = wave-uniform base + lane*16.
#define GLDS16(g, l)                                                           \
  __builtin_amdgcn_global_load_lds(                                           \
      (const __attribute__((address_space(1))) void*)(g),                     \
      (__attribute__((address_space(3))) void*)(l), 16, 0, 0)

__device__ inline short f2b(float f) {
  __hip_bfloat16 h = __float2bfloat16(f);
  short s;
  __builtin_memcpy(&s, &h, 2);
  return s;
}

// Load 16 contiguous fp32, convert to bf16, store 32B to LDS (two b128).
__device__ inline void stage16(const float* gp, __hip_bfloat16* lp) {
  float4 q0 = ((const float4*)gp)[0], q1 = ((const float4*)gp)[1];
  float4 q2 = ((const float4*)gp)[2], q3 = ((const float4*)gp)[3];
  bf16x8 v0, v1;
  v0[0] = f2b(q0.x); v0[1] = f2b(q0.y); v0[2] = f2b(q0.z); v0[3] = f2b(q0.w);
  v0[4] = f2b(q1.x); v0[5] = f2b(q1.y); v0[6] = f2b(q1.z); v0[7] = f2b(q1.w);
  v1[0] = f2b(q2.x); v1[1] = f2b(q2.y); v1[2] = f2b(q2.z); v1[3] = f2b(q2.w);
  v1[4] = f2b(q3.x); v1[5] = f2b(q3.y); v1[6] = f2b(q3.z); v1[7] = f2b(q3.w);
  *(bf16x8*)lp = v0;
  *(bf16x8*)(lp + 8) = v1;
}

// Per-batch output slice base, dtype-aware (fl=1: bf16, fl=0: fp32).
__device__ inline char* out_slice(void* outv, int b, int fl) {
  return (char*)outv + (size_t)b * (size_t)SEQ * DIM * (fl ? 2u : 4u);
}

// ---------------------------------------------------------------------------
// Detect input dtype from w_qkv bit patterns; canonicalize qw/kw to bf16.
// ---------------------------------------------------------------------------
__global__ __launch_bounds__(256)
void detect_canon(const unsigned int* __restrict__ wbits,
                  const void* __restrict__ qw, const void* __restrict__ kw,
                  __hip_bfloat16* __restrict__ qwb,
                  __hip_bfloat16* __restrict__ kwb, int* __restrict__ flag) {
  __shared__ int cnt;
  const int t = threadIdx.x;
  if (t == 0) cnt = 0;
  __syncthreads();
  int local = 0;
  for (int i = 0; i < 4; ++i) {
    unsigned int e = (wbits[t * 4 + i] >> 7) & 0xFF;
    if (e >= 96 && e < 160) local++;
  }
  atomicAdd(&cnt, local);
  __syncthreads();
  const int f = (cnt >= 768) ? 1 : 0;  // 1 = bf16 tensors, 0 = fp32 tensors
  if (t == 0) *flag = f;
  if (t < 128)
    qwb[t] = f ? ((const __hip_bfloat16*)qw)[t]
               : __float2bfloat16(((const float*)qw)[t]);
  else
    kwb[t - 128] = f ? ((const __hip_bfloat16*)kw)[t - 128]
                     : __float2bfloat16(((const float*)kw)[t - 128]);
}

// ---------------------------------------------------------------------------
// Elementwise canonicalize a tensor to bf16 (8 elts/thread). fl=1: raw copy.
// ---------------------------------------------------------------------------
__global__ __launch_bounds__(256)
void convert_bf16(const void* __restrict__ in, __hip_bfloat16* __restrict__ out,
                  const int* __restrict__ flag) {
  const int fl = *flag;
  long i = ((long)blockIdx.x * 256 + threadIdx.x) * 8;
  if (fl) {
    *(float4*)(out + i) = *(const float4*)((const __hip_bfloat16*)in + i);
  } else {
    const float* p = (const float*)in + i;
    float4 a = ((const float4*)p)[0], b = ((const float4*)p)[1];
    bf16x8 o;
    o[0] = f2b(a.x); o[1] = f2b(a.y); o[2] = f2b(a.z); o[3] = f2b(a.w);
    o[4] = f2b(b.x); o[5] = f2b(b.y); o[6] = f2b(b.z); o[7] = f2b(b.w);
    *(bf16x8*)(out + i) = o;
  }
}

// ===========================================================================
// TIER A GEMMs (m97 structure, both operands via global_load_lds).
// ===========================================================================

__global__ __launch_bounds__(256)
void gemm_qkv_full(const __hip_bfloat16* __restrict__ A,
                   const __hip_bfloat16* __restrict__ B,
                   __hip_bfloat16* __restrict__ qk, void* __restrict__ outv,
                   const int* __restrict__ flag) {
  __shared__ __hip_bfloat16 As[128 * 32];
  __shared__ __hip_bfloat16 Bs[128 * 32];
  const int t = threadIdx.x, wave = t >> 6, lane = t & 63;
  const int quad = lane >> 4, l16 = lane & 15;
  const int wm = (wave & 1) * 64, wn = (wave >> 1) * 64;
  const long bm = (long)blockIdx.x * 128, bn = (long)blockIdx.y * 128;
  const int fl = *flag;

  f32x4 acc[4][4] = {};
  for (int k0 = 0; k0 < DIM; k0 += 32) {
    __syncthreads();
    for (int i = 0; i < 2; ++i) {
      int c = wave * 64 + lane + i * 256;
      int row = c >> 2, kc = c & 3;
      GLDS16(A + (bm + row) * DIM + k0 + kc * 8, As + (wave * 64 + i * 256) * 8);
      GLDS16(B + (bn + row) * DIM + k0 + kc * 8, Bs + (wave * 64 + i * 256) * 8);
    }
    __syncthreads();
    bf16x8 aF[4], bF[4];
    for (int mt = 0; mt < 4; ++mt)
      aF[mt] = *(const bf16x8*)(As + (wm + mt * 16 + l16) * 32 + quad * 8);
    for (int nt = 0; nt < 4; ++nt)
      bF[nt] = *(const bf16x8*)(Bs + (wn + nt * 16 + l16) * 32 + quad * 8);
    for (int mt = 0; mt < 4; ++mt)
      for (int nt = 0; nt < 4; ++nt)
        acc[mt][nt] = __builtin_amdgcn_mfma_f32_16x16x32_bf16(
            aF[mt], bF[nt], acc[mt][nt], 0, 0, 0);
  }

  if (bn < 4096) {  // Q|K block
    for (int mt = 0; mt < 4; ++mt) {
      long gr = bm + wm + mt * 16 + quad * 4;
      for (int nt = 0; nt < 4; ++nt) {
        long gc = bn + wn + nt * 16 + l16;
        for (int r = 0; r < 4; ++r)
          qk[(gr + r) * QK_LD + gc] = __float2bfloat16(acc[mt][nt][r]);
      }
    }
  } else {  // V block: transposed bf16 store into the owning batch's slice
    for (int mt = 0; mt < 4; ++mt) {
      long gr = bm + wm + mt * 16 + quad * 4;
      __hip_bfloat16* vtb = (__hip_bfloat16*)out_slice(outv, (int)(gr >> 11), fl);
      long s = gr & 2047;
      for (int nt = 0; nt < 4; ++nt) {
        long col = bn - 4096 + wn + nt * 16 + l16;  // h*128 + d
        for (int r = 0; r < 4; ++r)
          vtb[col * SEQ + s + r] = __float2bfloat16(acc[mt][nt][r]);
      }
    }
  }
}

__global__ __launch_bounds__(256)
void gemm_proj_full(const __hip_bfloat16* __restrict__ A,
                    const __hip_bfloat16* __restrict__ B,
                    void* __restrict__ outv, const int* __restrict__ flag) {
  __shared__ __hip_bfloat16 As[128 * 32];
  __shared__ __hip_bfloat16 Bs[128 * 32];
  const int t = threadIdx.x, wave = t >> 6, lane = t & 63;
  const int quad = lane >> 4, l16 = lane & 15;
  const int wm = (wave & 1) * 64, wn = (wave >> 1) * 64;
  const long bm = (long)blockIdx.x * 128, bn = (long)blockIdx.y * 128;
  const int fl = *flag;

  f32x4 acc[4][4] = {};
  for (int k0 = 0; k0 < DIM; k0 += 32) {
    __syncthreads();
    for (int i = 0; i < 2; ++i) {
      int c = wave * 64 + lane + i * 256;
      int row = c >> 2, kc = c & 3;
      GLDS16(A + (bm + row) * QK_LD + k0 + kc * 8, As + (wave * 64 + i * 256) * 8);
      GLDS16(B + (bn + row) * DIM + k0 + kc * 8, Bs + (wave * 64 + i * 256) * 8);
    }
    __syncthreads();
    bf16x8 aF[4], bF[4];
    for (int mt = 0; mt < 4; ++mt)
      aF[mt] = *(const bf16x8*)(As + (wm + mt * 16 + l16) * 32 + quad * 8);
    for (int nt = 0; nt < 4; ++nt)
      bF[nt] = *(const bf16x8*)(Bs + (wn + nt * 16 + l16) * 32 + quad * 8);
    for (int mt = 0; mt < 4; ++mt)
      for (int nt = 0; nt < 4; ++nt)
        acc[mt][nt] = __builtin_amdgcn_mfma_f32_16x16x32_bf16(
            aF[mt], bF[nt], acc[mt][nt], 0, 0, 0);
  }

  for (int mt = 0; mt < 4; ++mt) {
    long gr = bm + wm + mt * 16 + quad * 4;
    for (int nt = 0; nt < 4; ++nt) {
      long gc = bn + wn + nt * 16 + l16;
      for (int r = 0; r < 4; ++r) {
        long idx = (gr + r) * DIM + gc;
        if (fl) ((__hip_bfloat16*)outv)[idx] = __float2bfloat16(acc[mt][nt][r]);
        else    ((float*)outv)[idx] = acc[mt][nt][r];
      }
    }
  }
}

// ===========================================================================
// TIER B GEMMs (per-batch, dual staging — fallback, known-good).
// ===========================================================================

__global__ __launch_bounds__(256)
void gemm_qkv(const void* __restrict__ xin, const void* __restrict__ win,
              __hip_bfloat16* __restrict__ qk, void* __restrict__ outv,
              const int* __restrict__ flag, int b) {
  __shared__ __hip_bfloat16 As[128 * 32];
  __shared__ __hip_bfloat16 Bs[128 * 32];
  const int t = threadIdx.x, wave = t >> 6, lane = t & 63;
  const int quad = lane >> 4, l16 = lane & 15;
  const int wm = (wave & 1) * 64, wn = (wave >> 1) * 64;
  const long bm = (long)blockIdx.x * 128, bn = (long)blockIdx.y * 128;
  const int fl = *flag;
  const __hip_bfloat16* Ab = (const __hip_bfloat16*)xin + (long)b * SEQ * DIM;
  const __hip_bfloat16* Bb = (const __hip_bfloat16*)win;
  const float* Af = (const float*)xin + (long)b * SEQ * DIM;
  const float* Bf = (const float*)win;

  f32x4 acc[4][4] = {};
  for (int k0 = 0; k0 < DIM; k0 += 32) {
    __syncthreads();
    if (fl) {
      for (int i = 0; i < 2; ++i) {
        int c = wave * 64 + lane + i * 256;
        int row = c >> 2, kc = c & 3;
        GLDS16(Ab + (bm + row) * DIM + k0 + kc * 8, As + (wave * 64 + i * 256) * 8);
        GLDS16(Bb + (bn + row) * DIM + k0 + kc * 8, Bs + (wave * 64 + i * 256) * 8);
      }
    } else {
      int row = t >> 1, cb = k0 + (t & 1) * 16;
      stage16(Af + (bm + row) * DIM + cb, As + t * 16);
      stage16(Bf + (bn + row) * DIM + cb, Bs + t * 16);
    }
    __syncthreads();
    bf16x8 aF[4], bF[4];
    for (int mt = 0; mt < 4; ++mt)
      aF[mt] = *(const bf16x8*)(As + (wm + mt * 16 + l16) * 32 + quad * 8);
    for (int nt = 0; nt < 4; ++nt)
      bF[nt] = *(const bf16x8*)(Bs + (wn + nt * 16 + l16) * 32 + quad * 8);
    for (int mt = 0; mt < 4; ++mt)
      for (int nt = 0; nt < 4; ++nt)
        acc[mt][nt] = __builtin_amdgcn_mfma_f32_16x16x32_bf16(
            aF[mt], bF[nt], acc[mt][nt], 0, 0, 0);
  }

  if (bn < 4096) {
    for (int mt = 0; mt < 4; ++mt) {
      long gr = bm + wm + mt * 16 + quad * 4;
      for (int nt = 0; nt < 4; ++nt) {
        long gc = bn + wn + nt * 16 + l16;
        for (int r = 0; r < 4; ++r)
          qk[(gr + r) * QK_LD + gc] = __float2bfloat16(acc[mt][nt][r]);
      }
    }
  } else {
    __hip_bfloat16* vtb = (__hip_bfloat16*)out_slice(outv, b, fl);
    for (int mt = 0; mt < 4; ++mt) {
      long gr = bm + wm + mt * 16 + quad * 4;
      for (int nt = 0; nt < 4; ++nt) {
        long col = bn - 4096 + wn + nt * 16 + l16;
        for (int r = 0; r < 4; ++r)
          vtb[col * SEQ + gr + r] = __float2bfloat16(acc[mt][nt][r]);
      }
    }
  }
}

__global__ __launch_bounds__(256)
void gemm_proj(const __hip_bfloat16* __restrict__ A, const void* __restrict__ win,
               void* __restrict__ outv, const int* __restrict__ flag, int b) {
  __shared__ __hip_bfloat16 As[128 * 32];
  __shared__ __hip_bfloat16 Bs[128 * 32];
  const int t = threadIdx.x, wave = t >> 6, lane = t & 63;
  const int quad = lane >> 4, l16 = lane & 15;
  const int wm = (wave & 1) * 64, wn = (wave >> 1) * 64;
  const long bm = (long)blockIdx.x * 128, bn = (long)blockIdx.y * 128;
  const int fl = *flag;
  const __hip_bfloat16* Bb = (const __hip_bfloat16*)win;
  const float* Bf = (const float*)win;

  f32x4 acc[4][4] = {};
  for (int k0 = 0; k0 < DIM; k0 += 32) {
    __syncthreads();
    for (int i = 0; i < 2; ++i) {
      int c = wave * 64 + lane + i * 256;
      int row = c >> 2, kc = c & 3;
      GLDS16(A + (bm + row) * QK_LD + k0 + kc * 8, As + (wave * 64 + i * 256) * 8);
    }
    if (fl) {
      for (int i = 0; i < 2; ++i) {
        int c = wave * 64 + lane + i * 256;
        int row = c >> 2, kc = c & 3;
        GLDS16(Bb + (bn + row) * DIM + k0 + kc * 8, Bs + (wave * 64 + i * 256) * 8);
      }
    } else {
      int row = t >> 1, cb = k0 + (t & 1) * 16;
      stage16(Bf + (bn + row) * DIM + cb, Bs + t * 16);
    }
    __syncthreads();
    bf16x8 aF[4], bF[4];
    for (int mt = 0; mt < 4; ++mt)
      aF[mt] = *(const bf16x8*)(As + (wm + mt * 16 + l16) * 32 + quad * 8);
    for (int nt = 0; nt < 4; ++nt)
      bF[nt] = *(const bf16x8*)(Bs + (wn + nt * 16 + l16) * 32 + quad * 8);
    for (int mt = 0; mt < 4; ++mt)
      for (int nt = 0; nt < 4; ++nt)
        acc[mt][nt] = __builtin_amdgcn_mfma_f32_16x16x32_bf16(
            aF[mt], bF[nt], acc[mt][nt], 0, 0, 0);
  }

  char* Cb = out_slice(outv, b, fl);
  for (int mt = 0; mt < 4; ++mt) {
    long gr = bm + wm + mt * 16 + quad * 4;
    for (int nt = 0; nt < 4; ++nt) {
      long gc = bn + wn + nt * 16 + l16;
      for (int r = 0; r < 4; ++r) {
        long idx = (gr + r) * DIM + gc;
        if (fl) ((__hip_bfloat16*)Cb)[idx] = __float2bfloat16(acc[mt][nt][r]);
        else    ((float*)Cb)[idx] = acc[mt][nt][r];
      }
    }
  }
}

// ===========================================================================
// Shared kernels.
// ===========================================================================

// Per-row RMSNorm + RoPE, vectorized: lane loads uint (2 bf16), shfl
// redistributes to the (d, d+64) RoPE pairing, inverse shfl scatters back.
__global__ __launch_bounds__(256)
void norm_rope(__hip_bfloat16* __restrict__ qk,
               const __hip_bfloat16* __restrict__ qwb,
               const __hip_bfloat16* __restrict__ kwb) {
  const int wave = threadIdx.x >> 6, lane = threadIdx.x & 63;
  const int gid = blockIdx.x * 4 + wave;
  const int h = gid & 15, tt = (gid >> 4) & 1, row = gid >> 5;
  const int s = row & 2047;

  __hip_bfloat16* p = qk + (long)row * QK_LD + tt * DIM + h * HD;
  unsigned int u = ((const unsigned int*)p)[lane];  // elems (2l, 2l+1)

  // gather pair (d=lane, d=lane+64)
  unsigned int x = (unsigned int)__shfl((int)u, lane >> 1);
  unsigned int y = (unsigned int)__shfl((int)u, 32 + (lane >> 1));
  float v1 = __uint_as_float((lane & 1) ? (x & 0xFFFF0000u) : (x << 16));
  float v2 = __uint_as_float((lane & 1) ? (y & 0xFFFF0000u) : (y << 16));

  float ss = v1 * v1 + v2 * v2;
  for (int off = 1; off < 64; off <<= 1) ss += __shfl_xor(ss, off);
  float inv = rsqrtf(ss * (1.0f / 128.0f) + 1e-6f);

  const __hip_bfloat16* w = tt ? kwb : qwb;
  float n1 = v1 * inv * __bfloat162float(w[lane]);
  float n2 = v2 * inv * __bfloat162float(w[lane + 64]);

  float freq = exp2f(-5.0f * (float)lane * (1.0f / 64.0f));
  float ang = (float)s * freq;
  float c = cosf(ang), sn = sinf(ang);
  float r1 = n1 * c - n2 * sn;  // elem d = lane
  float r2 = n2 * c + n1 * sn;  // elem d = lane + 64

  // scatter back: lane stores elems (2l, 2l+1)
  float z1lo = __shfl(r1, (2 * lane) & 63), z2lo = __shfl(r2, (2 * lane) & 63);
  float z1hi = __shfl(r1, (2 * lane + 1) & 63), z2hi = __shfl(r2, (2 * lane + 1) & 63);
  float lo = (lane < 32) ? z1lo : z2lo;
  float hi = (lane < 32) ? z1hi : z2hi;
  unsigned int ou = (unsigned int)(unsigned short)f2b(lo) |
                    ((unsigned int)(unsigned short)f2b(hi) << 16);
  ((unsigned int*)p)[lane] = ou;
}

// ---------------------------------------------------------------------------
// Flash attention, non-causal. Block = 128-query tile for one (b,h);
// 4 waves x 32 query rows. Q held in registers (loaded once). K-tiles of 64.
// batch = b0 + blockIdx.z; qk batch stride SEQ*QK_LD. Output in place into
// the Q-slot (block-exclusive region). LDS 48 KB -> 3 blocks/CU possible.
// ---------------------------------------------------------------------------
__global__ __launch_bounds__(256)
void flash_attn(__hip_bfloat16* __restrict__ qkbase, void* __restrict__ outv,
                const int* __restrict__ flag, int b0) {
  __shared__ __hip_bfloat16 Ks[4 * 64 * 32];     // [ks=4][krow=64][32]
  __shared__ __hip_bfloat16 Vs[2 * 128 * 32];    // [ks2=2][dim=128][32 keys]
  __shared__ __hip_bfloat16 Ps[4][2 * 32 * 32];  // per-wave [ks2=2][row=32][32]

  const int t = threadIdx.x, wave = t >> 6, lane = t & 63;
  const int quad = lane >> 4, l16 = lane & 15;
  const int q0 = blockIdx.x * 128, h = blockIdx.y;
  const int b = b0 + blockIdx.z;
  const int fl = *flag;
  __hip_bfloat16* qk = qkbase + (long)blockIdx.z * SEQ * QK_LD;
  __hip_bfloat16* Qg = qk + h * HD;
  const __hip_bfloat16* Kg = Qg + DIM;
  const __hip_bfloat16* Vt =
      (const __hip_bfloat16*)out_slice(outv, b, fl) + (long)h * HD * SEQ;

  // Q fragments in registers: aQ[mt][ks], rows wave*32 + mt*16 + l16
  bf16x8 aQ[2][4];
#pragma unroll
  for (int mt = 0; mt < 2; ++mt)
#pragma unroll
    for (int ks = 0; ks < 4; ++ks)
      aQ[mt][ks] = *(const bf16x8*)(Qg +
          (long)(q0 + wave * 32 + mt * 16 + l16) * QK_LD + ks * 32 + quad * 8);

  f32x4 oacc[2][8] = {};
  float m_run[2][4], l_run[2][4];
#pragma unroll
  for (int mt = 0; mt < 2; ++mt)
    for (int r = 0; r < 4; ++r) { m_run[mt][r] = -1e30f; l_run[mt][r] = 0.0f; }

  for (int j0 = 0; j0 < SEQ; j0 += 64) {
    __syncthreads();  // all waves done reading Ks/Vs of previous tile
    for (int i = 0; i < 4; ++i) {
      int f = wave * 64 + lane + i * 256;          // [0,1024)
      int kk = f & 3, row = (f >> 2) & 63, ks = f >> 8;
      GLDS16(Kg + (long)(j0 + row) * QK_LD + ks * 32 + kk * 8,
             Ks + (wave * 64 + i * 256) * 8);
    }
    for (int i = 0; i < 4; ++i) {
      int f = wave * 64 + lane + i * 256;
      int kk = f & 3, dimr = (f >> 2) & 127, ks2 = f >> 9;
      GLDS16(Vt + (long)dimr * SEQ + j0 + ks2 * 32 + kk * 8,
             Vs + (wave * 64 + i * 256) * 8);
    }
    __syncthreads();  // drains vmcnt (GLDS) + barrier

    // S = Q K^T: 32 rows x 64 keys per wave
    f32x4 sacc[2][4] = {};
#pragma unroll
    for (int ks = 0; ks < 4; ++ks)
#pragma unroll
      for (int nt = 0; nt < 4; ++nt) {
        bf16x8 bK = *(const bf16x8*)(Ks + (ks * 64 + nt * 16 + l16) * 32 + quad * 8);
#pragma unroll
        for (int mt = 0; mt < 2; ++mt)
          sacc[mt][nt] = __builtin_amdgcn_mfma_f32_16x16x32_bf16(
              aQ[mt][ks], bK, sacc[mt][nt], 0, 0, 0);
      }

    // online softmax per (mt, r); stats reduced across the 16-lane quad
    __hip_bfloat16* pw = &Ps[wave][0];
#pragma unroll
    for (int mt = 0; mt < 2; ++mt) {
      float p[4][4];
      for (int r = 0; r < 4; ++r) {
        float mx = -1e30f;
        for (int nt = 0; nt < 4; ++nt) {
          float sv = sacc[mt][nt][r] * SCALE;
          p[nt][r] = sv;
          mx = fmaxf(mx, sv);
        }
        for (int off = 1; off < 16; off <<= 1) mx = fmaxf(mx, __shfl_xor(mx, off));
        float mnew = fmaxf(m_run[mt][r], mx);
        float sum = 0.0f;
        for (int nt = 0; nt < 4; ++nt) {
          float e = __expf(p[nt][r] - mnew);
          p[nt][r] = e;
          sum += e;
        }
        for (int off = 1; off < 16; off <<= 1) sum += __shfl_xor(sum, off);
        float alpha = __expf(m_run[mt][r] - mnew);
        l_run[mt][r] = l_run[mt][r] * alpha + sum;
        m_run[mt][r] = mnew;
        for (int n = 0; n < 8; ++n) oacc[mt][n][r] = oacc[mt][n][r] * alpha;
      }
      // P: C-layout -> A-layout, wave-private LDS (no barrier needed)
      for (int r = 0; r < 4; ++r)
        for (int nt = 0; nt < 4; ++nt)
          pw[((nt >> 1) * 32 + mt * 16 + quad * 4 + r) * 32 + (nt & 1) * 16 + l16] =
              __float2bfloat16(p[nt][r]);
    }

    // O += P @ V  (intra-wave LDS RAW ordered by lgkmcnt, not __syncthreads)
#pragma unroll
    for (int ks2 = 0; ks2 < 2; ++ks2) {
      bf16x8 aP[2];
#pragma unroll
      for (int mt = 0; mt < 2; ++mt)
        aP[mt] = *(const bf16x8*)(pw + (ks2 * 32 + mt * 16 + l16) * 32 + quad * 8);
#pragma unroll
      for (int n = 0; n < 8; ++n) {
        bf16x8 bV = *(const bf16x8*)(Vs + (ks2 * 128 + n * 16 + l16) * 32 + quad * 8);
#pragma unroll
        for (int mt = 0; mt < 2; ++mt)
          oacc[mt][n] = __builtin_amdgcn_mfma_f32_16x16x32_bf16(
              aP[mt], bV, oacc[mt][n], 0, 0, 0);
      }
    }
  }

  // epilogue: write O into this block's exclusive Q-slot region
#pragma unroll
  for (int mt = 0; mt < 2; ++mt)
    for (int r = 0; r < 4; ++r) {
      float rl = 1.0f / l_run[mt][r];
      long s = q0 + wave * 32 + mt * 16 + quad * 4 + r;
      for (int n = 0; n < 8; ++n)
        qk[s * QK_LD + h * HD + n * 16 + l16] =
            __float2bfloat16(oacc[mt][n][r] * rl);
    }
}

// ---------------------------------------------------------------------------
extern "C" void kernel_launch(void* const* d_in, const int* in_sizes, int n_in,
                              void* d_out, int out_size, void* d_ws, size_t ws_size,
                              hipStream_t stream) {
  int* flag = (int*)d_ws;
  __hip_bfloat16* qwb = (__hip_bfloat16*)((char*)d_ws + 64);
  __hip_bfloat16* kwb = qwb + 128;
  char* base = (char*)d_ws + 1024;

  detect_canon<<<1, 256, 0, stream>>>((const unsigned int*)d_in[1], d_in[3],
                                      d_in[4], qwb, kwb, flag);

  const size_t MB = 1024ull * 1024ull;
  const size_t NEED_A = 1024 + 128 * MB;

  if (ws_size >= NEED_A) {
    // ---- Tier A: full-batch bf16 path ----
    __hip_bfloat16* xb     = (__hip_bfloat16*)base;              // 32 MiB
    __hip_bfloat16* wqkvb  = (__hip_bfloat16*)(base + 32 * MB);  // 24 MiB
    __hip_bfloat16* wprojb = (__hip_bfloat16*)(base + 56 * MB);  //  8 MiB
    __hip_bfloat16* qk     = (__hip_bfloat16*)(base + 64 * MB);  // 64 MiB

    convert_bf16<<<(BSZ * SEQ * DIM) / 2048, 256, 0, stream>>>(d_in[0], xb, flag);
    convert_bf16<<<(3 * DIM * DIM) / 2048, 256, 0, stream>>>(d_in[1], wqkvb, flag);
    convert_bf16<<<(DIM * DIM) / 2048, 256, 0, stream>>>(d_in[2], wprojb, flag);

    gemm_qkv_full<<<dim3((BSZ * SEQ) / 128, (3 * DIM) / 128), 256, 0, stream>>>(
        xb, wqkvb, qk, d_out, flag);
    norm_rope<<<(BSZ * SEQ * 2 * NH) / 4, 256, 0, stream>>>(qk, qwb, kwb);
    flash_attn<<<dim3(SEQ / 128, NH, BSZ), 256, 0, stream>>>(qk, d_out, flag, 0);
    gemm_proj_full<<<dim3((BSZ * SEQ) / 128, DIM / 128), 256, 0, stream>>>(
        qk, wprojb, d_out, flag);
  } else {
    // ---- Tier B: per-batch fallback ----
    __hip_bfloat16* qk = (__hip_bfloat16*)base;  // 16 MiB, reused per batch
    for (int b = 0; b < BSZ; ++b) {
      gemm_qkv<<<dim3(SEQ / 128, (3 * DIM) / 128), 256, 0, stream>>>(
          d_in[0], d_in[1], qk, d_out, flag, b);
      norm_rope<<<(SEQ * 2 * NH) / 4, 256, 0, stream>>>(qk, qwb, kwb);
      flash_attn<<<dim3(SEQ / 128, NH, 1), 256, 0, stream>>>(qk, d_out, flag, b);
      gemm_proj<<<dim3(SEQ / 128, DIM / 128), 256, 0, stream>>>(
          qk, d_in[2], d_out, flag, b);
    }
  }
}